// Round 5
// baseline (547.538 us; speedup 1.0000x reference)
//
#include <hip/hip_runtime.h>
#include <cstdint>
#include <cstddef>

// ---- bf16 pack/unpack helpers (RNE) ----
static __device__ __forceinline__ unsigned int f2bf_rne(float f) {
    unsigned int u = __float_as_uint(f);
    unsigned int r = 0x7FFFu + ((u >> 16) & 1u);
    return (u + r) >> 16;
}
static __device__ __forceinline__ unsigned int pack_bf2(float lo, float hi) {
    return f2bf_rne(lo) | (f2bf_rne(hi) << 16);
}
static __device__ __forceinline__ float bf_lo(unsigned int w) {
    return __uint_as_float(w << 16);
}
static __device__ __forceinline__ float bf_hi(unsigned int w) {
    return __uint_as_float(w & 0xFFFF0000u);
}

// ---------------- CSR build ----------------

__global__ void k_detect64(const unsigned int* ei, int e, int* is64) {
    __shared__ int nonzero;
    if (threadIdx.x == 0) nonzero = 0;
    __syncthreads();
    for (int i = threadIdx.x; i < 4096; i += blockDim.x) {
        size_t k = (size_t)((unsigned long long)i * (unsigned long long)e / 4096ull);
        if (ei[2 * k + 1] != 0u) nonzero = 1;   // racy OR, fine
    }
    __syncthreads();
    if (threadIdx.x == 0) *is64 = nonzero ? 0 : 1;
}

__global__ void k_init_deg(int* deg, int n) {
    int i = blockIdx.x * blockDim.x + threadIdx.x;
    if (i < n) deg[i] = 1;   // self-loop
}

__global__ void k_cvt_count(const void* ei_raw, int e, const int* is64,
                            int* __restrict__ src32, int* __restrict__ dst32,
                            int* __restrict__ deg) {
    int i = blockIdx.x * blockDim.x + threadIdx.x;
    if (i >= e) return;
    int s, d;
    if (*is64) {
        const long long* p = (const long long*)ei_raw;
        s = (int)p[i];
        d = (int)p[(size_t)e + i];
    } else {
        const int* p = (const int*)ei_raw;
        s = p[i];
        d = p[(size_t)e + i];
    }
    src32[i] = s;
    dst32[i] = d;
    atomicAdd(&deg[d], 1);
}

// --- 3-phase parallel exclusive scan of (deg[i]-1), 1024 elems/block ---
__global__ __launch_bounds__(1024) void k_scan1(const int* __restrict__ deg,
                                                int* __restrict__ row_ptr,
                                                int* __restrict__ gsum,
                                                float* __restrict__ dinv, int n) {
    __shared__ int s[1024];
    int t = threadIdx.x;
    int i = blockIdx.x * 1024 + t;
    int v = 0;
    if (i < n) {
        int d = deg[i];
        v = d - 1;
        dinv[i] = rsqrtf((float)d);
    }
    s[t] = v;
    __syncthreads();
    #pragma unroll
    for (int d = 1; d < 1024; d <<= 1) {
        int tmp = (t >= d) ? s[t - d] : 0;
        __syncthreads();
        s[t] += tmp;
        __syncthreads();
    }
    if (i < n) row_ptr[i] = s[t] - v;
    if (t == 1023) gsum[blockIdx.x] = s[1023];
}

__global__ __launch_bounds__(1024) void k_scan2(const int* __restrict__ gsum,
                                                int* __restrict__ gbase,
                                                int* __restrict__ row_ptr,
                                                int nb, int n) {
    __shared__ int s[1024];
    int t = threadIdx.x;
    int v = (t < nb) ? gsum[t] : 0;
    s[t] = v;
    __syncthreads();
    #pragma unroll
    for (int d = 1; d < 1024; d <<= 1) {
        int tmp = (t >= d) ? s[t - d] : 0;
        __syncthreads();
        s[t] += tmp;
        __syncthreads();
    }
    if (t < nb) gbase[t] = s[t] - v;
    if (t == 1023) row_ptr[n] = s[1023];
}

__global__ void k_scan3(int* __restrict__ row_ptr, int* __restrict__ cursor,
                        const int* __restrict__ gbase, int n) {
    int i = blockIdx.x * blockDim.x + threadIdx.x;
    if (i >= n) return;
    int v = row_ptr[i] + gbase[i >> 10];
    row_ptr[i] = v;
    cursor[i]  = v;
}

// XCD-affinity scatter. R4 lesson: the write window (1.6 MB/XCD) DOES fit L2,
// but the 25.6 MB/XCD src/dst read stream thrashed it (WRITE_SIZE 173 MB for a
// 12.8 MB payload). Fix: non-temporal reads (evict-first, no L2 allocate) so
// partially-filled write lines survive until full. Stores stay cached.
__global__ __launch_bounds__(256) void k_scatter_xcd(const int* __restrict__ src,
                                                     const int* __restrict__ dst, int e,
                                                     int* __restrict__ cursor,
                                                     int* __restrict__ src_sorted, int n) {
    int xcd = blockIdx.x & 7;
    int lo_node = (int)((long long)xcd * n / 8);
    int hi_node = (int)((long long)(xcd + 1) * n / 8);
    int nblk = gridDim.x >> 3;
    int bid  = blockIdx.x >> 3;
    int step = nblk * blockDim.x;
    for (int i = bid * blockDim.x + threadIdx.x; i < e; i += step) {
        int d = __builtin_nontemporal_load(&dst[i]);
        int s = __builtin_nontemporal_load(&src[i]);
        if (d >= lo_node && d < hi_node) {
            int pos = atomicAdd(&cursor[d], 1);
            src_sorted[pos] = s;
        }
    }
}

// ---------------- GEMMs (f32 VALU, LDS-tiled) ----------------
// Epilogue scales by dinv[row] and packs to bf16 pairs (halves gather bytes
// downstream: R3 k_agg1 was L3-service-bound at 786MB FETCH, 3.85 TB/s).

// hsb[m][c/2] = pack_bf16( dinv[m] * (A[m]@W)[c..c+1] ), K=128, N=128.
__global__ __launch_bounds__(256) void k_gemm128(const float* __restrict__ A,
                                                 const float* __restrict__ W,
                                                 const float* __restrict__ dinv,
                                                 unsigned int* __restrict__ hsb, int M) {
    __shared__ float sA[64][36];
    __shared__ float sW[32][128];
    int tid = threadIdx.x;
    int tx = tid & 15;   // cols tx*8 .. +7
    int ty = tid >> 4;   // rows ty*4 .. +3
    int row0 = blockIdx.x * 64;
    float acc[4][8] = {};
    for (int k0 = 0; k0 < 128; k0 += 32) {
        __syncthreads();
        for (int i = tid; i < 512; i += 256) {
            int r = i >> 3, c4 = i & 7;
            float4 v = {0.f, 0.f, 0.f, 0.f};
            int gr = row0 + r;
            if (gr < M) v = *reinterpret_cast<const float4*>(&A[(size_t)gr * 128 + k0 + c4 * 4]);
            *reinterpret_cast<float4*>(&sA[r][c4 * 4]) = v;
        }
        for (int i = tid; i < 1024; i += 256) {
            int r = i >> 5, c4 = i & 31;
            *reinterpret_cast<float4*>(&sW[r][c4 * 4]) =
                *reinterpret_cast<const float4*>(&W[(size_t)(k0 + r) * 128 + c4 * 4]);
        }
        __syncthreads();
        #pragma unroll
        for (int k = 0; k < 32; k += 4) {
            float4 a[4];
            #pragma unroll
            for (int r = 0; r < 4; ++r)
                a[r] = *reinterpret_cast<const float4*>(&sA[ty * 4 + r][k]);
            #pragma unroll
            for (int kk = 0; kk < 4; ++kk) {
                float4 w0 = *reinterpret_cast<const float4*>(&sW[k + kk][tx * 8]);
                float4 w1 = *reinterpret_cast<const float4*>(&sW[k + kk][tx * 8 + 4]);
                #pragma unroll
                for (int r = 0; r < 4; ++r) {
                    float av = (&a[r].x)[kk];
                    acc[r][0] += av * w0.x; acc[r][1] += av * w0.y;
                    acc[r][2] += av * w0.z; acc[r][3] += av * w0.w;
                    acc[r][4] += av * w1.x; acc[r][5] += av * w1.y;
                    acc[r][6] += av * w1.z; acc[r][7] += av * w1.w;
                }
            }
        }
    }
    #pragma unroll
    for (int r = 0; r < 4; ++r) {
        int gr = row0 + ty * 4 + r;
        if (gr < M) {
            float di = dinv[gr];
            uint4 o;
            o.x = pack_bf2(acc[r][0] * di, acc[r][1] * di);
            o.y = pack_bf2(acc[r][2] * di, acc[r][3] * di);
            o.z = pack_bf2(acc[r][4] * di, acc[r][5] * di);
            o.w = pack_bf2(acc[r][6] * di, acc[r][7] * di);
            *reinterpret_cast<uint4*>(&hsb[(size_t)gr * 64 + tx * 4]) = o;
        }
    }
}

// zsb[m][c/2] = pack_bf16( dinv[m] * (A[m]@W)[c..c+1] ), K=128, N=64. A is f32.
__global__ __launch_bounds__(256) void k_gemm64(const float* __restrict__ A,
                                                const float* __restrict__ W,
                                                const float* __restrict__ dinv,
                                                unsigned int* __restrict__ zsb, int M) {
    __shared__ float sA[64][36];
    __shared__ float sW[32][64];
    int tid = threadIdx.x;
    int tx = tid & 15;   // cols tx*4 .. +3
    int ty = tid >> 4;   // rows ty*4 .. +3
    int row0 = blockIdx.x * 64;
    float acc[4][4] = {};
    for (int k0 = 0; k0 < 128; k0 += 32) {
        __syncthreads();
        for (int i = tid; i < 512; i += 256) {
            int r = i >> 3, c4 = i & 7;
            float4 v = {0.f, 0.f, 0.f, 0.f};
            int gr = row0 + r;
            if (gr < M) v = *reinterpret_cast<const float4*>(&A[(size_t)gr * 128 + k0 + c4 * 4]);
            *reinterpret_cast<float4*>(&sA[r][c4 * 4]) = v;
        }
        for (int i = tid; i < 512; i += 256) {
            int r = i >> 4, c4 = i & 15;
            *reinterpret_cast<float4*>(&sW[r][c4 * 4]) =
                *reinterpret_cast<const float4*>(&W[(size_t)(k0 + r) * 64 + c4 * 4]);
        }
        __syncthreads();
        #pragma unroll
        for (int k = 0; k < 32; k += 4) {
            float4 a[4];
            #pragma unroll
            for (int r = 0; r < 4; ++r)
                a[r] = *reinterpret_cast<const float4*>(&sA[ty * 4 + r][k]);
            #pragma unroll
            for (int kk = 0; kk < 4; ++kk) {
                float4 w = *reinterpret_cast<const float4*>(&sW[k + kk][tx * 4]);
                #pragma unroll
                for (int r = 0; r < 4; ++r) {
                    float av = (&a[r].x)[kk];
                    acc[r][0] += av * w.x; acc[r][1] += av * w.y;
                    acc[r][2] += av * w.z; acc[r][3] += av * w.w;
                }
            }
        }
    }
    #pragma unroll
    for (int r = 0; r < 4; ++r) {
        int gr = row0 + ty * 4 + r;
        if (gr < M) {
            float di = dinv[gr];
            uint2 o;
            o.x = pack_bf2(acc[r][0] * di, acc[r][1] * di);
            o.y = pack_bf2(acc[r][2] * di, acc[r][3] * di);
            *reinterpret_cast<uint2*>(&zsb[(size_t)gr * 32 + tx * 2]) = o;
        }
    }
}

// ---------------- Aggregation ----------------
// bf16x2 payload: one dword per thread per row; f32 accumulate; x8 unroll
// keeps 8 row-loads in flight (R1 lesson: serial chain = latency-bound).

// h2[i][2c..2c+1] = relu( dinv[i]*(hsb_sum) + b1 ), one wave per node.
__global__ __launch_bounds__(64) void k_agg1(const unsigned int* __restrict__ hsb,
                                             const float* __restrict__ dinv,
                                             const int* __restrict__ row_ptr,
                                             const int* __restrict__ src_sorted,
                                             const float* __restrict__ b1,
                                             float* __restrict__ h2) {
    int i = blockIdx.x;
    int c = threadIdx.x;          // channel pair 2c, 2c+1
    unsigned int w = hsb[(size_t)i * 64 + c];
    float ax = bf_lo(w), ay = bf_hi(w);
    int lo = row_ptr[i], hi = row_ptr[i + 1];
    int e = lo;
    for (; e + 8 <= hi; e += 8) {
        int s0 = src_sorted[e + 0], s1 = src_sorted[e + 1];
        int s2 = src_sorted[e + 2], s3 = src_sorted[e + 3];
        int s4 = src_sorted[e + 4], s5 = src_sorted[e + 5];
        int s6 = src_sorted[e + 6], s7 = src_sorted[e + 7];
        unsigned int w0 = hsb[(size_t)s0 * 64 + c];
        unsigned int w1 = hsb[(size_t)s1 * 64 + c];
        unsigned int w2 = hsb[(size_t)s2 * 64 + c];
        unsigned int w3 = hsb[(size_t)s3 * 64 + c];
        unsigned int w4 = hsb[(size_t)s4 * 64 + c];
        unsigned int w5 = hsb[(size_t)s5 * 64 + c];
        unsigned int w6 = hsb[(size_t)s6 * 64 + c];
        unsigned int w7 = hsb[(size_t)s7 * 64 + c];
        ax += ((bf_lo(w0) + bf_lo(w1)) + (bf_lo(w2) + bf_lo(w3)))
            + ((bf_lo(w4) + bf_lo(w5)) + (bf_lo(w6) + bf_lo(w7)));
        ay += ((bf_hi(w0) + bf_hi(w1)) + (bf_hi(w2) + bf_hi(w3)))
            + ((bf_hi(w4) + bf_hi(w5)) + (bf_hi(w6) + bf_hi(w7)));
    }
    if (e + 4 <= hi) {
        int s0 = src_sorted[e + 0], s1 = src_sorted[e + 1];
        int s2 = src_sorted[e + 2], s3 = src_sorted[e + 3];
        unsigned int w0 = hsb[(size_t)s0 * 64 + c];
        unsigned int w1 = hsb[(size_t)s1 * 64 + c];
        unsigned int w2 = hsb[(size_t)s2 * 64 + c];
        unsigned int w3 = hsb[(size_t)s3 * 64 + c];
        ax += (bf_lo(w0) + bf_lo(w1)) + (bf_lo(w2) + bf_lo(w3));
        ay += (bf_hi(w0) + bf_hi(w1)) + (bf_hi(w2) + bf_hi(w3));
        e += 4;
    }
    for (; e < hi; ++e) {
        int s = src_sorted[e];
        unsigned int ws = hsb[(size_t)s * 64 + c];
        ax += bf_lo(ws);
        ay += bf_hi(ws);
    }
    float di = dinv[i];
    float2 bb = *reinterpret_cast<const float2*>(&b1[2 * c]);
    float v0 = di * ax + bb.x;
    float v1 = di * ay + bb.y;
    float2 o = {v0 > 0.f ? v0 : 0.f, v1 > 0.f ? v1 : 0.f};
    *reinterpret_cast<float2*>(&h2[(size_t)i * 128 + 2 * c]) = o;
}

// out[i][2c..2c+1] = dinv[i]*(zsb_sum) + b2; 2 nodes per 64-thread block.
__global__ __launch_bounds__(64) void k_agg2(const unsigned int* __restrict__ zsb,
                                             const float* __restrict__ dinv,
                                             const int* __restrict__ row_ptr,
                                             const int* __restrict__ src_sorted,
                                             const float* __restrict__ b2,
                                             float* __restrict__ out, int n) {
    int i = blockIdx.x * 2 + (threadIdx.x >> 5);
    int c = threadIdx.x & 31;     // channel pair 2c, 2c+1
    if (i >= n) return;
    unsigned int w = zsb[(size_t)i * 32 + c];
    float ax = bf_lo(w), ay = bf_hi(w);
    int lo = row_ptr[i], hi = row_ptr[i + 1];
    int e = lo;
    for (; e + 8 <= hi; e += 8) {
        int s0 = src_sorted[e + 0], s1 = src_sorted[e + 1];
        int s2 = src_sorted[e + 2], s3 = src_sorted[e + 3];
        int s4 = src_sorted[e + 4], s5 = src_sorted[e + 5];
        int s6 = src_sorted[e + 6], s7 = src_sorted[e + 7];
        unsigned int w0 = zsb[(size_t)s0 * 32 + c];
        unsigned int w1 = zsb[(size_t)s1 * 32 + c];
        unsigned int w2 = zsb[(size_t)s2 * 32 + c];
        unsigned int w3 = zsb[(size_t)s3 * 32 + c];
        unsigned int w4 = zsb[(size_t)s4 * 32 + c];
        unsigned int w5 = zsb[(size_t)s5 * 32 + c];
        unsigned int w6 = zsb[(size_t)s6 * 32 + c];
        unsigned int w7 = zsb[(size_t)s7 * 32 + c];
        ax += ((bf_lo(w0) + bf_lo(w1)) + (bf_lo(w2) + bf_lo(w3)))
            + ((bf_lo(w4) + bf_lo(w5)) + (bf_lo(w6) + bf_lo(w7)));
        ay += ((bf_hi(w0) + bf_hi(w1)) + (bf_hi(w2) + bf_hi(w3)))
            + ((bf_hi(w4) + bf_hi(w5)) + (bf_hi(w6) + bf_hi(w7)));
    }
    if (e + 4 <= hi) {
        int s0 = src_sorted[e + 0], s1 = src_sorted[e + 1];
        int s2 = src_sorted[e + 2], s3 = src_sorted[e + 3];
        unsigned int w0 = zsb[(size_t)s0 * 32 + c];
        unsigned int w1 = zsb[(size_t)s1 * 32 + c];
        unsigned int w2 = zsb[(size_t)s2 * 32 + c];
        unsigned int w3 = zsb[(size_t)s3 * 32 + c];
        ax += (bf_lo(w0) + bf_lo(w1)) + (bf_lo(w2) + bf_lo(w3));
        ay += (bf_hi(w0) + bf_hi(w1)) + (bf_hi(w2) + bf_hi(w3));
        e += 4;
    }
    for (; e < hi; ++e) {
        int s = src_sorted[e];
        unsigned int ws = zsb[(size_t)s * 32 + c];
        ax += bf_lo(ws);
        ay += bf_hi(ws);
    }
    float di = dinv[i];
    float2 bb = *reinterpret_cast<const float2*>(&b2[2 * c]);
    float2 o = {di * ax + bb.x, di * ay + bb.y};
    *reinterpret_cast<float2*>(&out[(size_t)i * 64 + 2 * c]) = o;
}

// ---------------- launch ----------------

static inline size_t alignup(size_t v) { return (v + 255) & ~(size_t)255; }

extern "C" void kernel_launch(void* const* d_in, const int* in_sizes, int n_in,
                              void* d_out, int out_size, void* d_ws, size_t ws_size,
                              hipStream_t stream) {
    const float* x  = (const float*)d_in[0];
    const void*  ei = d_in[1];
    const float* W1 = (const float*)d_in[2];
    const float* b1 = (const float*)d_in[3];
    const float* W2 = (const float*)d_in[4];
    const float* b2 = (const float*)d_in[5];

    const int n = in_sizes[0] / 128;   // 100000
    const int e = in_sizes[1] / 2;     // 3200000

    char* p = (char*)d_ws;
    auto take = [&](size_t bytes) { char* q = p; p += alignup(bytes); return q; };
    int*          is64       = (int*)         take(4);
    int*          src32      = (int*)         take((size_t)e * 4);
    int*          dst32      = (int*)         take((size_t)e * 4);
    int*          deg        = (int*)         take((size_t)n * 4);
    float*        dinv       = (float*)       take((size_t)n * 4);
    int*          row_ptr    = (int*)         take((size_t)(n + 1) * 4);
    int*          cursor     = (int*)         take((size_t)n * 4);
    int*          gsum       = (int*)         take(1024 * 4);
    int*          gbase      = (int*)         take(1024 * 4);
    int*          src_sorted = (int*)         take((size_t)e * 4);
    unsigned int* hsb        = (unsigned int*)take((size_t)n * 64 * 4);   // bf16x2 [n][64]
    float*        h2         = (float*)       take((size_t)n * 128 * 4);
    unsigned int* zsb        = (unsigned int*)take((size_t)n * 32 * 4);   // bf16x2 [n][32]
    if ((size_t)(p - (char*)d_ws) > ws_size) return;

    const int nb_e = (e + 255) / 256;
    const int nb_n = (n + 255) / 256;
    const int nb_scan = (n + 1023) / 1024;   // 98 for n=100000 (<=1024)

    k_detect64<<<1, 256, 0, stream>>>((const unsigned int*)ei, e, is64);
    k_init_deg<<<nb_n, 256, 0, stream>>>(deg, n);
    k_cvt_count<<<nb_e, 256, 0, stream>>>(ei, e, is64, src32, dst32, deg);
    k_scan1<<<nb_scan, 1024, 0, stream>>>(deg, row_ptr, gsum, dinv, n);
    k_scan2<<<1, 1024, 0, stream>>>(gsum, gbase, row_ptr, nb_scan, n);
    k_scan3<<<nb_n, 256, 0, stream>>>(row_ptr, cursor, gbase, n);
    k_scatter_xcd<<<2048, 256, 0, stream>>>(src32, dst32, e, cursor, src_sorted, n);

    k_gemm128<<<(n + 63) / 64, 256, 0, stream>>>(x, W1, dinv, hsb, n);
    k_agg1<<<n, 64, 0, stream>>>(hsb, dinv, row_ptr, src_sorted, b1, h2);
    k_gemm64<<<(n + 63) / 64, 256, 0, stream>>>(h2, W2, dinv, zsb, n);
    k_agg2<<<(n + 1) / 2, 64, 0, stream>>>(zsb, dinv, row_ptr, src_sorted, b2, (float*)d_out, n);
}

// Round 6
// 525.922 us; speedup vs baseline: 1.0411x; 1.0411x over previous
//
#include <hip/hip_runtime.h>
#include <cstdint>
#include <cstddef>

// ---- bf16 pack/unpack helpers (RNE) ----
static __device__ __forceinline__ unsigned int f2bf_rne(float f) {
    unsigned int u = __float_as_uint(f);
    unsigned int r = 0x7FFFu + ((u >> 16) & 1u);
    return (u + r) >> 16;
}
static __device__ __forceinline__ unsigned int pack_bf2(float lo, float hi) {
    return f2bf_rne(lo) | (f2bf_rne(hi) << 16);
}
static __device__ __forceinline__ float bf_lo(unsigned int w) {
    return __uint_as_float(w << 16);
}
static __device__ __forceinline__ float bf_hi(unsigned int w) {
    return __uint_as_float(w & 0xFFFF0000u);
}

// ---------------- CSR build ----------------

__global__ void k_detect64(const unsigned int* ei, int e, int* is64) {
    __shared__ int nonzero;
    if (threadIdx.x == 0) nonzero = 0;
    __syncthreads();
    for (int i = threadIdx.x; i < 4096; i += blockDim.x) {
        size_t k = (size_t)((unsigned long long)i * (unsigned long long)e / 4096ull);
        if (ei[2 * k + 1] != 0u) nonzero = 1;   // racy OR, fine
    }
    __syncthreads();
    if (threadIdx.x == 0) *is64 = nonzero ? 0 : 1;
}

__global__ void k_init_deg(int* deg, int n) {
    int i = blockIdx.x * blockDim.x + threadIdx.x;
    if (i < n) deg[i] = 1;   // self-loop
}

// Convert + degree count; emits packed (dst<<32 | src) pairs for the sort.
__global__ void k_cvt_count(const void* ei_raw, int e, const int* is64,
                            unsigned long long* __restrict__ pairs,
                            int* __restrict__ deg) {
    int i = blockIdx.x * blockDim.x + threadIdx.x;
    if (i >= e) return;
    int s, d;
    if (*is64) {
        const long long* p = (const long long*)ei_raw;
        s = (int)p[i];
        d = (int)p[(size_t)e + i];
    } else {
        const int* p = (const int*)ei_raw;
        s = p[i];
        d = p[(size_t)e + i];
    }
    pairs[i] = ((unsigned long long)(unsigned int)d << 32) | (unsigned int)s;
    atomicAdd(&deg[d], 1);
}

// --- 3-phase parallel exclusive scan of (deg[i]-1), 1024 elems/block ---
__global__ __launch_bounds__(1024) void k_scan1(const int* __restrict__ deg,
                                                int* __restrict__ row_ptr,
                                                int* __restrict__ gsum,
                                                float* __restrict__ dinv, int n) {
    __shared__ int s[1024];
    int t = threadIdx.x;
    int i = blockIdx.x * 1024 + t;
    int v = 0;
    if (i < n) {
        int d = deg[i];
        v = d - 1;
        dinv[i] = rsqrtf((float)d);
    }
    s[t] = v;
    __syncthreads();
    #pragma unroll
    for (int d = 1; d < 1024; d <<= 1) {
        int tmp = (t >= d) ? s[t - d] : 0;
        __syncthreads();
        s[t] += tmp;
        __syncthreads();
    }
    if (i < n) row_ptr[i] = s[t] - v;
    if (t == 1023) gsum[blockIdx.x] = s[1023];
}

__global__ __launch_bounds__(1024) void k_scan2(const int* __restrict__ gsum,
                                                int* __restrict__ gbase,
                                                int* __restrict__ row_ptr,
                                                int nb, int n) {
    __shared__ int s[1024];
    int t = threadIdx.x;
    int v = (t < nb) ? gsum[t] : 0;
    s[t] = v;
    __syncthreads();
    #pragma unroll
    for (int d = 1; d < 1024; d <<= 1) {
        int tmp = (t >= d) ? s[t - d] : 0;
        __syncthreads();
        s[t] += tmp;
        __syncthreads();
    }
    if (t < nb) gbase[t] = s[t] - v;
    if (t == 1023) row_ptr[n] = s[1023];
}

// Phase 3: add block base; materialize cursor; init bucket cursors
// (bucket b = nodes [b*256, b*256+256), so its base is row_ptr[b*256]).
__global__ void k_scan3(int* __restrict__ row_ptr, int* __restrict__ cursor,
                        const int* __restrict__ gbase,
                        int* __restrict__ bkt_cursor, int n) {
    int i = blockIdx.x * blockDim.x + threadIdx.x;
    if (i >= n) return;
    int v = row_ptr[i] + gbase[i >> 10];
    row_ptr[i] = v;
    cursor[i]  = v;
    if ((i & 255) == 0) bkt_cursor[i >> 8] = v;
}

// ---------------- Two-pass bucket sort (replaces R3-R5 k_scatter_xcd) ----------------
// R5 lesson: XCD-affinity windows did NOT merge (WRITE 131MB for 12.8MB payload)
// because blockIdx&7 does not confine a window to one L2. Fix: make write
// locality structural, not mapping-dependent.

// Pass A: one block per 16K-edge chunk. LDS histogram over dst>>8 buckets ->
// one global atomicAdd reservation per (block,bucket) -> re-read chunk and
// write pairs at reserved offsets. Runs of ~42 edges (336B) are line-friendly;
// only ~77K global atomics total.
#define BKT_CH 16384
__global__ __launch_bounds__(256) void k_bucket(const unsigned long long* __restrict__ pin,
                                                int e, int nb,
                                                int* __restrict__ bkt_cursor,
                                                unsigned long long* __restrict__ pout) {
    __shared__ int lcnt[512];
    __shared__ int lbase[512];
    int t = threadIdx.x;
    int lo = blockIdx.x * BKT_CH;
    int hi = lo + BKT_CH; if (hi > e) hi = e;
    for (int j = t; j < 512; j += 256) lcnt[j] = 0;
    __syncthreads();
    for (int i = lo + t; i < hi; i += 256) {
        unsigned long long pr = __builtin_nontemporal_load(&pin[i]);
        int b = (int)(pr >> 40);            // dst >> 8
        atomicAdd(&lcnt[b], 1);
    }
    __syncthreads();
    for (int j = t; j < 512; j += 256) {
        int c = lcnt[j];
        lbase[j] = (c > 0 && j < nb) ? atomicAdd(&bkt_cursor[j], c) : 0;
        lcnt[j] = 0;                        // becomes running offset for phase 3
    }
    __syncthreads();
    for (int i = lo + t; i < hi; i += 256) {
        unsigned long long pr = __builtin_nontemporal_load(&pin[i]);
        int b = (int)(pr >> 40);
        int pos = lbase[b] + atomicAdd(&lcnt[b], 1);
        pout[pos] = pr;
    }
}

// Pass B: one block per bucket. The block's src_sorted window (~33 KB) is
// touched by exactly one block -> one L2 -> stores merge into full lines.
__global__ __launch_bounds__(256) void k_place(const unsigned long long* __restrict__ pairs,
                                               const int* __restrict__ row_ptr,
                                               int n, int* __restrict__ cursor,
                                               int* __restrict__ src_sorted) {
    int b = blockIdx.x;
    int lo_node = b << 8;
    int hi_node = lo_node + 256; if (hi_node > n) hi_node = n;
    int base = row_ptr[lo_node], end = row_ptr[hi_node];
    for (int i = base + threadIdx.x; i < end; i += 256) {
        unsigned long long pr = pairs[i];
        int d = (int)(pr >> 32);
        int s = (int)(pr & 0xFFFFFFFFu);
        int pos = atomicAdd(&cursor[d], 1);
        src_sorted[pos] = s;
    }
}

// ---------------- GEMMs (f32 VALU, LDS-tiled) ----------------
// Epilogue scales by dinv[row] and packs to bf16 pairs (halves gather bytes
// downstream: R3 k_agg1 was L3-service-bound at 786MB FETCH, 3.85 TB/s).

// hsb[m][c/2] = pack_bf16( dinv[m] * (A[m]@W)[c..c+1] ), K=128, N=128.
__global__ __launch_bounds__(256) void k_gemm128(const float* __restrict__ A,
                                                 const float* __restrict__ W,
                                                 const float* __restrict__ dinv,
                                                 unsigned int* __restrict__ hsb, int M) {
    __shared__ float sA[64][36];
    __shared__ float sW[32][128];
    int tid = threadIdx.x;
    int tx = tid & 15;   // cols tx*8 .. +7
    int ty = tid >> 4;   // rows ty*4 .. +3
    int row0 = blockIdx.x * 64;
    float acc[4][8] = {};
    for (int k0 = 0; k0 < 128; k0 += 32) {
        __syncthreads();
        for (int i = tid; i < 512; i += 256) {
            int r = i >> 3, c4 = i & 7;
            float4 v = {0.f, 0.f, 0.f, 0.f};
            int gr = row0 + r;
            if (gr < M) v = *reinterpret_cast<const float4*>(&A[(size_t)gr * 128 + k0 + c4 * 4]);
            *reinterpret_cast<float4*>(&sA[r][c4 * 4]) = v;
        }
        for (int i = tid; i < 1024; i += 256) {
            int r = i >> 5, c4 = i & 31;
            *reinterpret_cast<float4*>(&sW[r][c4 * 4]) =
                *reinterpret_cast<const float4*>(&W[(size_t)(k0 + r) * 128 + c4 * 4]);
        }
        __syncthreads();
        #pragma unroll
        for (int k = 0; k < 32; k += 4) {
            float4 a[4];
            #pragma unroll
            for (int r = 0; r < 4; ++r)
                a[r] = *reinterpret_cast<const float4*>(&sA[ty * 4 + r][k]);
            #pragma unroll
            for (int kk = 0; kk < 4; ++kk) {
                float4 w0 = *reinterpret_cast<const float4*>(&sW[k + kk][tx * 8]);
                float4 w1 = *reinterpret_cast<const float4*>(&sW[k + kk][tx * 8 + 4]);
                #pragma unroll
                for (int r = 0; r < 4; ++r) {
                    float av = (&a[r].x)[kk];
                    acc[r][0] += av * w0.x; acc[r][1] += av * w0.y;
                    acc[r][2] += av * w0.z; acc[r][3] += av * w0.w;
                    acc[r][4] += av * w1.x; acc[r][5] += av * w1.y;
                    acc[r][6] += av * w1.z; acc[r][7] += av * w1.w;
                }
            }
        }
    }
    #pragma unroll
    for (int r = 0; r < 4; ++r) {
        int gr = row0 + ty * 4 + r;
        if (gr < M) {
            float di = dinv[gr];
            uint4 o;
            o.x = pack_bf2(acc[r][0] * di, acc[r][1] * di);
            o.y = pack_bf2(acc[r][2] * di, acc[r][3] * di);
            o.z = pack_bf2(acc[r][4] * di, acc[r][5] * di);
            o.w = pack_bf2(acc[r][6] * di, acc[r][7] * di);
            *reinterpret_cast<uint4*>(&hsb[(size_t)gr * 64 + tx * 4]) = o;
        }
    }
}

// zsb[m][c/2] = pack_bf16( dinv[m] * (A[m]@W)[c..c+1] ), K=128, N=64. A is f32.
__global__ __launch_bounds__(256) void k_gemm64(const float* __restrict__ A,
                                                const float* __restrict__ W,
                                                const float* __restrict__ dinv,
                                                unsigned int* __restrict__ zsb, int M) {
    __shared__ float sA[64][36];
    __shared__ float sW[32][64];
    int tid = threadIdx.x;
    int tx = tid & 15;   // cols tx*4 .. +3
    int ty = tid >> 4;   // rows ty*4 .. +3
    int row0 = blockIdx.x * 64;
    float acc[4][4] = {};
    for (int k0 = 0; k0 < 128; k0 += 32) {
        __syncthreads();
        for (int i = tid; i < 512; i += 256) {
            int r = i >> 3, c4 = i & 7;
            float4 v = {0.f, 0.f, 0.f, 0.f};
            int gr = row0 + r;
            if (gr < M) v = *reinterpret_cast<const float4*>(&A[(size_t)gr * 128 + k0 + c4 * 4]);
            *reinterpret_cast<float4*>(&sA[r][c4 * 4]) = v;
        }
        for (int i = tid; i < 512; i += 256) {
            int r = i >> 4, c4 = i & 15;
            *reinterpret_cast<float4*>(&sW[r][c4 * 4]) =
                *reinterpret_cast<const float4*>(&W[(size_t)(k0 + r) * 64 + c4 * 4]);
        }
        __syncthreads();
        #pragma unroll
        for (int k = 0; k < 32; k += 4) {
            float4 a[4];
            #pragma unroll
            for (int r = 0; r < 4; ++r)
                a[r] = *reinterpret_cast<const float4*>(&sA[ty * 4 + r][k]);
            #pragma unroll
            for (int kk = 0; kk < 4; ++kk) {
                float4 w = *reinterpret_cast<const float4*>(&sW[k + kk][tx * 4]);
                #pragma unroll
                for (int r = 0; r < 4; ++r) {
                    float av = (&a[r].x)[kk];
                    acc[r][0] += av * w.x; acc[r][1] += av * w.y;
                    acc[r][2] += av * w.z; acc[r][3] += av * w.w;
                }
            }
        }
    }
    #pragma unroll
    for (int r = 0; r < 4; ++r) {
        int gr = row0 + ty * 4 + r;
        if (gr < M) {
            float di = dinv[gr];
            uint2 o;
            o.x = pack_bf2(acc[r][0] * di, acc[r][1] * di);
            o.y = pack_bf2(acc[r][2] * di, acc[r][3] * di);
            *reinterpret_cast<uint2*>(&zsb[(size_t)gr * 32 + tx * 2]) = o;
        }
    }
}

// ---------------- Aggregation ----------------
// bf16x2 payload: one dword per thread per row; f32 accumulate; x8 unroll
// keeps 8 row-loads in flight (R1 lesson: serial chain = latency-bound).

// h2[i][2c..2c+1] = relu( dinv[i]*(hsb_sum) + b1 ), one wave per node.
__global__ __launch_bounds__(64) void k_agg1(const unsigned int* __restrict__ hsb,
                                             const float* __restrict__ dinv,
                                             const int* __restrict__ row_ptr,
                                             const int* __restrict__ src_sorted,
                                             const float* __restrict__ b1,
                                             float* __restrict__ h2) {
    int i = blockIdx.x;
    int c = threadIdx.x;          // channel pair 2c, 2c+1
    unsigned int w = hsb[(size_t)i * 64 + c];
    float ax = bf_lo(w), ay = bf_hi(w);
    int lo = row_ptr[i], hi = row_ptr[i + 1];
    int e = lo;
    for (; e + 8 <= hi; e += 8) {
        int s0 = src_sorted[e + 0], s1 = src_sorted[e + 1];
        int s2 = src_sorted[e + 2], s3 = src_sorted[e + 3];
        int s4 = src_sorted[e + 4], s5 = src_sorted[e + 5];
        int s6 = src_sorted[e + 6], s7 = src_sorted[e + 7];
        unsigned int w0 = hsb[(size_t)s0 * 64 + c];
        unsigned int w1 = hsb[(size_t)s1 * 64 + c];
        unsigned int w2 = hsb[(size_t)s2 * 64 + c];
        unsigned int w3 = hsb[(size_t)s3 * 64 + c];
        unsigned int w4 = hsb[(size_t)s4 * 64 + c];
        unsigned int w5 = hsb[(size_t)s5 * 64 + c];
        unsigned int w6 = hsb[(size_t)s6 * 64 + c];
        unsigned int w7 = hsb[(size_t)s7 * 64 + c];
        ax += ((bf_lo(w0) + bf_lo(w1)) + (bf_lo(w2) + bf_lo(w3)))
            + ((bf_lo(w4) + bf_lo(w5)) + (bf_lo(w6) + bf_lo(w7)));
        ay += ((bf_hi(w0) + bf_hi(w1)) + (bf_hi(w2) + bf_hi(w3)))
            + ((bf_hi(w4) + bf_hi(w5)) + (bf_hi(w6) + bf_hi(w7)));
    }
    if (e + 4 <= hi) {
        int s0 = src_sorted[e + 0], s1 = src_sorted[e + 1];
        int s2 = src_sorted[e + 2], s3 = src_sorted[e + 3];
        unsigned int w0 = hsb[(size_t)s0 * 64 + c];
        unsigned int w1 = hsb[(size_t)s1 * 64 + c];
        unsigned int w2 = hsb[(size_t)s2 * 64 + c];
        unsigned int w3 = hsb[(size_t)s3 * 64 + c];
        ax += (bf_lo(w0) + bf_lo(w1)) + (bf_lo(w2) + bf_lo(w3));
        ay += (bf_hi(w0) + bf_hi(w1)) + (bf_hi(w2) + bf_hi(w3));
        e += 4;
    }
    for (; e < hi; ++e) {
        int s = src_sorted[e];
        unsigned int ws = hsb[(size_t)s * 64 + c];
        ax += bf_lo(ws);
        ay += bf_hi(ws);
    }
    float di = dinv[i];
    float2 bb = *reinterpret_cast<const float2*>(&b1[2 * c]);
    float v0 = di * ax + bb.x;
    float v1 = di * ay + bb.y;
    float2 o = {v0 > 0.f ? v0 : 0.f, v1 > 0.f ? v1 : 0.f};
    *reinterpret_cast<float2*>(&h2[(size_t)i * 128 + 2 * c]) = o;
}

// out[i][2c..2c+1] = dinv[i]*(zsb_sum) + b2; 2 nodes per 64-thread block.
__global__ __launch_bounds__(64) void k_agg2(const unsigned int* __restrict__ zsb,
                                             const float* __restrict__ dinv,
                                             const int* __restrict__ row_ptr,
                                             const int* __restrict__ src_sorted,
                                             const float* __restrict__ b2,
                                             float* __restrict__ out, int n) {
    int i = blockIdx.x * 2 + (threadIdx.x >> 5);
    int c = threadIdx.x & 31;     // channel pair 2c, 2c+1
    if (i >= n) return;
    unsigned int w = zsb[(size_t)i * 32 + c];
    float ax = bf_lo(w), ay = bf_hi(w);
    int lo = row_ptr[i], hi = row_ptr[i + 1];
    int e = lo;
    for (; e + 8 <= hi; e += 8) {
        int s0 = src_sorted[e + 0], s1 = src_sorted[e + 1];
        int s2 = src_sorted[e + 2], s3 = src_sorted[e + 3];
        int s4 = src_sorted[e + 4], s5 = src_sorted[e + 5];
        int s6 = src_sorted[e + 6], s7 = src_sorted[e + 7];
        unsigned int w0 = zsb[(size_t)s0 * 32 + c];
        unsigned int w1 = zsb[(size_t)s1 * 32 + c];
        unsigned int w2 = zsb[(size_t)s2 * 32 + c];
        unsigned int w3 = zsb[(size_t)s3 * 32 + c];
        unsigned int w4 = zsb[(size_t)s4 * 32 + c];
        unsigned int w5 = zsb[(size_t)s5 * 32 + c];
        unsigned int w6 = zsb[(size_t)s6 * 32 + c];
        unsigned int w7 = zsb[(size_t)s7 * 32 + c];
        ax += ((bf_lo(w0) + bf_lo(w1)) + (bf_lo(w2) + bf_lo(w3)))
            + ((bf_lo(w4) + bf_lo(w5)) + (bf_lo(w6) + bf_lo(w7)));
        ay += ((bf_hi(w0) + bf_hi(w1)) + (bf_hi(w2) + bf_hi(w3)))
            + ((bf_hi(w4) + bf_hi(w5)) + (bf_hi(w6) + bf_hi(w7)));
    }
    if (e + 4 <= hi) {
        int s0 = src_sorted[e + 0], s1 = src_sorted[e + 1];
        int s2 = src_sorted[e + 2], s3 = src_sorted[e + 3];
        unsigned int w0 = zsb[(size_t)s0 * 32 + c];
        unsigned int w1 = zsb[(size_t)s1 * 32 + c];
        unsigned int w2 = zsb[(size_t)s2 * 32 + c];
        unsigned int w3 = zsb[(size_t)s3 * 32 + c];
        ax += (bf_lo(w0) + bf_lo(w1)) + (bf_lo(w2) + bf_lo(w3));
        ay += (bf_hi(w0) + bf_hi(w1)) + (bf_hi(w2) + bf_hi(w3));
        e += 4;
    }
    for (; e < hi; ++e) {
        int s = src_sorted[e];
        unsigned int ws = zsb[(size_t)s * 32 + c];
        ax += bf_lo(ws);
        ay += bf_hi(ws);
    }
    float di = dinv[i];
    float2 bb = *reinterpret_cast<const float2*>(&b2[2 * c]);
    float2 o = {di * ax + bb.x, di * ay + bb.y};
    *reinterpret_cast<float2*>(&out[(size_t)i * 64 + 2 * c]) = o;
}

// ---------------- launch ----------------

static inline size_t alignup(size_t v) { return (v + 255) & ~(size_t)255; }

extern "C" void kernel_launch(void* const* d_in, const int* in_sizes, int n_in,
                              void* d_out, int out_size, void* d_ws, size_t ws_size,
                              hipStream_t stream) {
    const float* x  = (const float*)d_in[0];
    const void*  ei = d_in[1];
    const float* W1 = (const float*)d_in[2];
    const float* b1 = (const float*)d_in[3];
    const float* W2 = (const float*)d_in[4];
    const float* b2 = (const float*)d_in[5];

    const int n = in_sizes[0] / 128;   // 100000
    const int e = in_sizes[1] / 2;     // 3200000

    // Region aliasing: pairs arrays are dead once k_place finishes, before the
    // GEMMs run (stream-ordered), so hsb/h2 reuse their space.
    char* p = (char*)d_ws;
    auto take = [&](size_t bytes) { char* q = p; p += alignup(bytes); return q; };
    size_t pairs_bytes = (size_t)e * 8;            // 25.6 MB
    size_t hsb_bytes   = (size_t)n * 64 * 4;       // 25.6 MB
    size_t h2_bytes    = (size_t)n * 128 * 4;      // 51.2 MB
    size_t regA_bytes  = pairs_bytes > hsb_bytes ? pairs_bytes : hsb_bytes;
    size_t regB_bytes  = pairs_bytes > h2_bytes ? pairs_bytes : h2_bytes;
    char* regA = (char*)take(regA_bytes);          // pairs_cvt, later hsb
    char* regB = (char*)take(regB_bytes);          // pairs_bkt, later h2
    unsigned long long* pairs_cvt = (unsigned long long*)regA;
    unsigned long long* pairs_bkt = (unsigned long long*)regB;
    unsigned int*       hsb       = (unsigned int*)regA;
    float*              h2        = (float*)regB;

    int*          is64       = (int*)  take(4);
    int*          deg        = (int*)  take((size_t)n * 4);
    float*        dinv       = (float*)take((size_t)n * 4);
    int*          row_ptr    = (int*)  take((size_t)(n + 1) * 4);
    int*          cursor     = (int*)  take((size_t)n * 4);
    int*          gsum       = (int*)  take(1024 * 4);
    int*          gbase      = (int*)  take(1024 * 4);
    int*          bkt_cursor = (int*)  take(1024 * 4);
    int*          src_sorted = (int*)  take((size_t)e * 4);
    unsigned int* zsb        = (unsigned int*)take((size_t)n * 32 * 4);
    if ((size_t)(p - (char*)d_ws) > ws_size) return;  // ws too small -> fail loudly

    const int nb_e    = (e + 255) / 256;
    const int nb_n    = (n + 255) / 256;
    const int nb_scan = (n + 1023) / 1024;        // 98 (<=1024)
    const int nb_bkt  = (n + 255) >> 8;           // 391 buckets of 256 nodes
    const int nb_chnk = (e + BKT_CH - 1) / BKT_CH; // 196 chunks

    k_detect64<<<1, 256, 0, stream>>>((const unsigned int*)ei, e, is64);
    k_init_deg<<<nb_n, 256, 0, stream>>>(deg, n);
    k_cvt_count<<<nb_e, 256, 0, stream>>>(ei, e, is64, pairs_cvt, deg);
    k_scan1<<<nb_scan, 1024, 0, stream>>>(deg, row_ptr, gsum, dinv, n);
    k_scan2<<<1, 1024, 0, stream>>>(gsum, gbase, row_ptr, nb_scan, n);
    k_scan3<<<nb_n, 256, 0, stream>>>(row_ptr, cursor, gbase, bkt_cursor, n);
    k_bucket<<<nb_chnk, 256, 0, stream>>>(pairs_cvt, e, nb_bkt, bkt_cursor, pairs_bkt);
    k_place<<<nb_bkt, 256, 0, stream>>>(pairs_bkt, row_ptr, n, cursor, src_sorted);

    k_gemm128<<<(n + 63) / 64, 256, 0, stream>>>(x, W1, dinv, hsb, n);
    k_agg1<<<n, 64, 0, stream>>>(hsb, dinv, row_ptr, src_sorted, b1, h2);
    k_gemm64<<<(n + 63) / 64, 256, 0, stream>>>(h2, W2, dinv, zsb, n);
    k_agg2<<<(n + 1) / 2, 64, 0, stream>>>(zsb, dinv, row_ptr, src_sorted, b2, (float*)d_out, n);
}

// Round 7
// 363.931 us; speedup vs baseline: 1.5045x; 1.4451x over previous
//
#include <hip/hip_runtime.h>
#include <cstdint>
#include <cstddef>

// ---- bf16 pack/unpack helpers (RNE) ----
static __device__ __forceinline__ unsigned int f2bf_rne(float f) {
    unsigned int u = __float_as_uint(f);
    unsigned int r = 0x7FFFu + ((u >> 16) & 1u);
    return (u + r) >> 16;
}
static __device__ __forceinline__ unsigned int pack_bf2(float lo, float hi) {
    return f2bf_rne(lo) | (f2bf_rne(hi) << 16);
}
static __device__ __forceinline__ float bf_lo(unsigned int w) {
    return __uint_as_float(w << 16);
}
static __device__ __forceinline__ float bf_hi(unsigned int w) {
    return __uint_as_float(w & 0xFFFF0000u);
}

#define BKT_CH 16384   // edges per chunk-block in hist/bucket passes

// ---------------- CSR build ----------------
// R6 lesson: every per-edge GLOBAL atomic costs ~30B of HBM write traffic
// (k_cvt_count: 3.2M deg atomics -> 125MB WRITE, 132us). This pipeline has
// ZERO per-edge global atomics: bucket-level reservations are LDS-aggregated
// (77K atomics total), per-node counts/cursors live in LDS of the one block
// that owns the bucket.

__global__ void k_detect64(const unsigned int* ei, int e, int* is64) {
    __shared__ int nonzero;
    if (threadIdx.x == 0) nonzero = 0;
    __syncthreads();
    for (int i = threadIdx.x; i < 4096; i += blockDim.x) {
        size_t k = (size_t)((unsigned long long)i * (unsigned long long)e / 4096ull);
        if (ei[2 * k + 1] != 0u) nonzero = 1;   // racy OR, fine
    }
    __syncthreads();
    if (threadIdx.x == 0) *is64 = nonzero ? 0 : 1;
}

__global__ void k_zero512(int* p) { p[threadIdx.x] = 0; }

// Pass 0: bucket histogram (bucket = dst>>8). LDS-aggregated, one global
// atomic per (block,bucket).
__global__ __launch_bounds__(256) void k_hist(const void* ei_raw, int e, const int* is64,
                                              int* __restrict__ bkt_cnt) {
    __shared__ int lcnt[512];
    int t = threadIdx.x;
    for (int j = t; j < 512; j += 256) lcnt[j] = 0;
    __syncthreads();
    int lo = blockIdx.x * BKT_CH;
    int hi = lo + BKT_CH; if (hi > e) hi = e;
    if (*is64) {
        const long long* p = (const long long*)ei_raw;
        for (int i = lo + t; i < hi; i += 256)
            atomicAdd(&lcnt[((int)p[(size_t)e + i]) >> 8], 1);
    } else {
        const int* p = (const int*)ei_raw;
        for (int i = lo + t; i < hi; i += 256)
            atomicAdd(&lcnt[p[(size_t)e + i] >> 8], 1);
    }
    __syncthreads();
    for (int j = t; j < 512; j += 256)
        if (lcnt[j]) atomicAdd(&bkt_cnt[j], lcnt[j]);
}

// Exclusive scan of bucket counts -> bkt_base[0..nb], bkt_cursor. One block.
__global__ __launch_bounds__(512) void k_scan_bkt(const int* __restrict__ bkt_cnt,
                                                  int* __restrict__ bkt_base,
                                                  int* __restrict__ bkt_cursor, int nb) {
    __shared__ int s[512];
    int t = threadIdx.x;
    int v = (t < nb) ? bkt_cnt[t] : 0;
    s[t] = v;
    __syncthreads();
    #pragma unroll
    for (int d = 1; d < 512; d <<= 1) {
        int tmp = (t >= d) ? s[t - d] : 0;
        __syncthreads();
        s[t] += tmp;
        __syncthreads();
    }
    if (t < nb) {
        int b = s[t] - v;
        bkt_base[t]   = b;
        bkt_cursor[t] = b;
    }
    if (t == 511) bkt_base[nb] = s[511];   // grand total (bins >= nb are 0)
}

// Pass 1: bucket the (dst,src) pairs. One block per 16K-edge chunk; LDS
// histogram -> one reservation per (block,bucket) -> scatter at reserved
// offsets (runs of ~42 edges = line-friendly).
__global__ __launch_bounds__(256) void k_bucket(const void* ei_raw, int e, const int* is64,
                                                int* __restrict__ bkt_cursor,
                                                unsigned long long* __restrict__ pout) {
    __shared__ int lcnt[512];
    __shared__ int lbase[512];
    int t = threadIdx.x;
    int lo = blockIdx.x * BKT_CH;
    int hi = lo + BKT_CH; if (hi > e) hi = e;
    for (int j = t; j < 512; j += 256) lcnt[j] = 0;
    __syncthreads();
    bool w64 = (*is64 != 0);
    const long long* p64 = (const long long*)ei_raw;
    const int*       p32 = (const int*)ei_raw;
    for (int i = lo + t; i < hi; i += 256) {
        int d = w64 ? (int)p64[(size_t)e + i] : p32[(size_t)e + i];
        atomicAdd(&lcnt[d >> 8], 1);
    }
    __syncthreads();
    for (int j = t; j < 512; j += 256) {
        int c = lcnt[j];
        lbase[j] = c ? atomicAdd(&bkt_cursor[j], c) : 0;
        lcnt[j] = 0;                        // running offset for scatter
    }
    __syncthreads();
    for (int i = lo + t; i < hi; i += 256) {
        int s, d;
        if (w64) { s = (int)p64[i]; d = (int)p64[(size_t)e + i]; }
        else     { s = p32[i];      d = p32[(size_t)e + i]; }
        int b = d >> 8;
        int pos = lbase[b] + atomicAdd(&lcnt[b], 1);
        pout[pos] = ((unsigned long long)(unsigned int)d << 32) | (unsigned int)s;
    }
}

// Pass 2: one block per bucket (256 nodes). Per-node counts in LDS -> local
// scan gives row_ptr + dinv (deg = cnt + 1 self-loop); LDS cursors scatter
// src into src_sorted. The block's ~33KB window is touched by exactly one
// block -> stores merge into full lines.
__global__ __launch_bounds__(256) void k_place_deg(const unsigned long long* __restrict__ pairs,
                                                   const int* __restrict__ bkt_base,
                                                   int n, int nb,
                                                   int* __restrict__ row_ptr,
                                                   float* __restrict__ dinv,
                                                   int* __restrict__ src_sorted) {
    __shared__ int lcnt[256];
    __shared__ int ls[256];
    __shared__ int lcur[256];
    int b = blockIdx.x;
    int t = threadIdx.x;
    int base = bkt_base[b], end = bkt_base[b + 1];
    lcnt[t] = 0;
    __syncthreads();
    for (int i = base + t; i < end; i += 256)
        atomicAdd(&lcnt[(int)(pairs[i] >> 32) & 255], 1);
    __syncthreads();
    int v = lcnt[t];
    ls[t] = v;
    __syncthreads();
    #pragma unroll
    for (int d = 1; d < 256; d <<= 1) {
        int tmp = (t >= d) ? ls[t - d] : 0;
        __syncthreads();
        ls[t] += tmp;
        __syncthreads();
    }
    int nodebase = base + ls[t] - v;       // exclusive within bucket
    int node = (b << 8) + t;
    if (node < n) {
        row_ptr[node] = nodebase;
        dinv[node] = rsqrtf((float)(v + 1));
    }
    lcur[t] = nodebase;
    __syncthreads();
    for (int i = base + t; i < end; i += 256) {
        unsigned long long pr = pairs[i];
        int pos = atomicAdd(&lcur[(int)(pr >> 32) & 255], 1);
        src_sorted[pos] = (int)(pr & 0xFFFFFFFFu);
    }
    if (t == 0 && b == nb - 1) row_ptr[n] = end;
}

// ---------------- GEMMs (f32 VALU, LDS-tiled) ----------------
// Epilogue scales by dinv[row] and packs to bf16 pairs (halves gather bytes
// downstream: R3 k_agg1 was L3-service-bound at 786MB FETCH, 3.85 TB/s).

// hsb[m][c/2] = pack_bf16( dinv[m] * (A[m]@W)[c..c+1] ), K=128, N=128.
__global__ __launch_bounds__(256) void k_gemm128(const float* __restrict__ A,
                                                 const float* __restrict__ W,
                                                 const float* __restrict__ dinv,
                                                 unsigned int* __restrict__ hsb, int M) {
    __shared__ float sA[64][36];
    __shared__ float sW[32][128];
    int tid = threadIdx.x;
    int tx = tid & 15;   // cols tx*8 .. +7
    int ty = tid >> 4;   // rows ty*4 .. +3
    int row0 = blockIdx.x * 64;
    float acc[4][8] = {};
    for (int k0 = 0; k0 < 128; k0 += 32) {
        __syncthreads();
        for (int i = tid; i < 512; i += 256) {
            int r = i >> 3, c4 = i & 7;
            float4 v = {0.f, 0.f, 0.f, 0.f};
            int gr = row0 + r;
            if (gr < M) v = *reinterpret_cast<const float4*>(&A[(size_t)gr * 128 + k0 + c4 * 4]);
            *reinterpret_cast<float4*>(&sA[r][c4 * 4]) = v;
        }
        for (int i = tid; i < 1024; i += 256) {
            int r = i >> 5, c4 = i & 31;
            *reinterpret_cast<float4*>(&sW[r][c4 * 4]) =
                *reinterpret_cast<const float4*>(&W[(size_t)(k0 + r) * 128 + c4 * 4]);
        }
        __syncthreads();
        #pragma unroll
        for (int k = 0; k < 32; k += 4) {
            float4 a[4];
            #pragma unroll
            for (int r = 0; r < 4; ++r)
                a[r] = *reinterpret_cast<const float4*>(&sA[ty * 4 + r][k]);
            #pragma unroll
            for (int kk = 0; kk < 4; ++kk) {
                float4 w0 = *reinterpret_cast<const float4*>(&sW[k + kk][tx * 8]);
                float4 w1 = *reinterpret_cast<const float4*>(&sW[k + kk][tx * 8 + 4]);
                #pragma unroll
                for (int r = 0; r < 4; ++r) {
                    float av = (&a[r].x)[kk];
                    acc[r][0] += av * w0.x; acc[r][1] += av * w0.y;
                    acc[r][2] += av * w0.z; acc[r][3] += av * w0.w;
                    acc[r][4] += av * w1.x; acc[r][5] += av * w1.y;
                    acc[r][6] += av * w1.z; acc[r][7] += av * w1.w;
                }
            }
        }
    }
    #pragma unroll
    for (int r = 0; r < 4; ++r) {
        int gr = row0 + ty * 4 + r;
        if (gr < M) {
            float di = dinv[gr];
            uint4 o;
            o.x = pack_bf2(acc[r][0] * di, acc[r][1] * di);
            o.y = pack_bf2(acc[r][2] * di, acc[r][3] * di);
            o.z = pack_bf2(acc[r][4] * di, acc[r][5] * di);
            o.w = pack_bf2(acc[r][6] * di, acc[r][7] * di);
            *reinterpret_cast<uint4*>(&hsb[(size_t)gr * 64 + tx * 4]) = o;
        }
    }
}

// zsb[m][c/2] = pack_bf16( dinv[m] * (A[m]@W)[c..c+1] ), K=128, N=64. A is f32.
__global__ __launch_bounds__(256) void k_gemm64(const float* __restrict__ A,
                                                const float* __restrict__ W,
                                                const float* __restrict__ dinv,
                                                unsigned int* __restrict__ zsb, int M) {
    __shared__ float sA[64][36];
    __shared__ float sW[32][64];
    int tid = threadIdx.x;
    int tx = tid & 15;   // cols tx*4 .. +3
    int ty = tid >> 4;   // rows ty*4 .. +3
    int row0 = blockIdx.x * 64;
    float acc[4][4] = {};
    for (int k0 = 0; k0 < 128; k0 += 32) {
        __syncthreads();
        for (int i = tid; i < 512; i += 256) {
            int r = i >> 3, c4 = i & 7;
            float4 v = {0.f, 0.f, 0.f, 0.f};
            int gr = row0 + r;
            if (gr < M) v = *reinterpret_cast<const float4*>(&A[(size_t)gr * 128 + k0 + c4 * 4]);
            *reinterpret_cast<float4*>(&sA[r][c4 * 4]) = v;
        }
        for (int i = tid; i < 512; i += 256) {
            int r = i >> 4, c4 = i & 15;
            *reinterpret_cast<float4*>(&sW[r][c4 * 4]) =
                *reinterpret_cast<const float4*>(&W[(size_t)(k0 + r) * 64 + c4 * 4]);
        }
        __syncthreads();
        #pragma unroll
        for (int k = 0; k < 32; k += 4) {
            float4 a[4];
            #pragma unroll
            for (int r = 0; r < 4; ++r)
                a[r] = *reinterpret_cast<const float4*>(&sA[ty * 4 + r][k]);
            #pragma unroll
            for (int kk = 0; kk < 4; ++kk) {
                float4 w = *reinterpret_cast<const float4*>(&sW[k + kk][tx * 4]);
                #pragma unroll
                for (int r = 0; r < 4; ++r) {
                    float av = (&a[r].x)[kk];
                    acc[r][0] += av * w.x; acc[r][1] += av * w.y;
                    acc[r][2] += av * w.z; acc[r][3] += av * w.w;
                }
            }
        }
    }
    #pragma unroll
    for (int r = 0; r < 4; ++r) {
        int gr = row0 + ty * 4 + r;
        if (gr < M) {
            float di = dinv[gr];
            uint2 o;
            o.x = pack_bf2(acc[r][0] * di, acc[r][1] * di);
            o.y = pack_bf2(acc[r][2] * di, acc[r][3] * di);
            *reinterpret_cast<uint2*>(&zsb[(size_t)gr * 32 + tx * 2]) = o;
        }
    }
}

// ---------------- Aggregation ----------------
// bf16x2 payload: one dword per thread per row; f32 accumulate; x8 unroll
// keeps 8 row-loads in flight (R1 lesson: serial chain = latency-bound).

// h2[i][2c..2c+1] = relu( dinv[i]*(hsb_sum) + b1 ), one wave per node.
__global__ __launch_bounds__(64) void k_agg1(const unsigned int* __restrict__ hsb,
                                             const float* __restrict__ dinv,
                                             const int* __restrict__ row_ptr,
                                             const int* __restrict__ src_sorted,
                                             const float* __restrict__ b1,
                                             float* __restrict__ h2) {
    int i = blockIdx.x;
    int c = threadIdx.x;          // channel pair 2c, 2c+1
    unsigned int w = hsb[(size_t)i * 64 + c];
    float ax = bf_lo(w), ay = bf_hi(w);
    int lo = row_ptr[i], hi = row_ptr[i + 1];
    int e = lo;
    for (; e + 8 <= hi; e += 8) {
        int s0 = src_sorted[e + 0], s1 = src_sorted[e + 1];
        int s2 = src_sorted[e + 2], s3 = src_sorted[e + 3];
        int s4 = src_sorted[e + 4], s5 = src_sorted[e + 5];
        int s6 = src_sorted[e + 6], s7 = src_sorted[e + 7];
        unsigned int w0 = hsb[(size_t)s0 * 64 + c];
        unsigned int w1 = hsb[(size_t)s1 * 64 + c];
        unsigned int w2 = hsb[(size_t)s2 * 64 + c];
        unsigned int w3 = hsb[(size_t)s3 * 64 + c];
        unsigned int w4 = hsb[(size_t)s4 * 64 + c];
        unsigned int w5 = hsb[(size_t)s5 * 64 + c];
        unsigned int w6 = hsb[(size_t)s6 * 64 + c];
        unsigned int w7 = hsb[(size_t)s7 * 64 + c];
        ax += ((bf_lo(w0) + bf_lo(w1)) + (bf_lo(w2) + bf_lo(w3)))
            + ((bf_lo(w4) + bf_lo(w5)) + (bf_lo(w6) + bf_lo(w7)));
        ay += ((bf_hi(w0) + bf_hi(w1)) + (bf_hi(w2) + bf_hi(w3)))
            + ((bf_hi(w4) + bf_hi(w5)) + (bf_hi(w6) + bf_hi(w7)));
    }
    if (e + 4 <= hi) {
        int s0 = src_sorted[e + 0], s1 = src_sorted[e + 1];
        int s2 = src_sorted[e + 2], s3 = src_sorted[e + 3];
        unsigned int w0 = hsb[(size_t)s0 * 64 + c];
        unsigned int w1 = hsb[(size_t)s1 * 64 + c];
        unsigned int w2 = hsb[(size_t)s2 * 64 + c];
        unsigned int w3 = hsb[(size_t)s3 * 64 + c];
        ax += (bf_lo(w0) + bf_lo(w1)) + (bf_lo(w2) + bf_lo(w3));
        ay += (bf_hi(w0) + bf_hi(w1)) + (bf_hi(w2) + bf_hi(w3));
        e += 4;
    }
    for (; e < hi; ++e) {
        int s = src_sorted[e];
        unsigned int ws = hsb[(size_t)s * 64 + c];
        ax += bf_lo(ws);
        ay += bf_hi(ws);
    }
    float di = dinv[i];
    float2 bb = *reinterpret_cast<const float2*>(&b1[2 * c]);
    float v0 = di * ax + bb.x;
    float v1 = di * ay + bb.y;
    float2 o = {v0 > 0.f ? v0 : 0.f, v1 > 0.f ? v1 : 0.f};
    *reinterpret_cast<float2*>(&h2[(size_t)i * 128 + 2 * c]) = o;
}

// out[i][2c..2c+1] = dinv[i]*(zsb_sum) + b2; 2 nodes per 64-thread block.
__global__ __launch_bounds__(64) void k_agg2(const unsigned int* __restrict__ zsb,
                                             const float* __restrict__ dinv,
                                             const int* __restrict__ row_ptr,
                                             const int* __restrict__ src_sorted,
                                             const float* __restrict__ b2,
                                             float* __restrict__ out, int n) {
    int i = blockIdx.x * 2 + (threadIdx.x >> 5);
    int c = threadIdx.x & 31;     // channel pair 2c, 2c+1
    if (i >= n) return;
    unsigned int w = zsb[(size_t)i * 32 + c];
    float ax = bf_lo(w), ay = bf_hi(w);
    int lo = row_ptr[i], hi = row_ptr[i + 1];
    int e = lo;
    for (; e + 8 <= hi; e += 8) {
        int s0 = src_sorted[e + 0], s1 = src_sorted[e + 1];
        int s2 = src_sorted[e + 2], s3 = src_sorted[e + 3];
        int s4 = src_sorted[e + 4], s5 = src_sorted[e + 5];
        int s6 = src_sorted[e + 6], s7 = src_sorted[e + 7];
        unsigned int w0 = zsb[(size_t)s0 * 32 + c];
        unsigned int w1 = zsb[(size_t)s1 * 32 + c];
        unsigned int w2 = zsb[(size_t)s2 * 32 + c];
        unsigned int w3 = zsb[(size_t)s3 * 32 + c];
        unsigned int w4 = zsb[(size_t)s4 * 32 + c];
        unsigned int w5 = zsb[(size_t)s5 * 32 + c];
        unsigned int w6 = zsb[(size_t)s6 * 32 + c];
        unsigned int w7 = zsb[(size_t)s7 * 32 + c];
        ax += ((bf_lo(w0) + bf_lo(w1)) + (bf_lo(w2) + bf_lo(w3)))
            + ((bf_lo(w4) + bf_lo(w5)) + (bf_lo(w6) + bf_lo(w7)));
        ay += ((bf_hi(w0) + bf_hi(w1)) + (bf_hi(w2) + bf_hi(w3)))
            + ((bf_hi(w4) + bf_hi(w5)) + (bf_hi(w6) + bf_hi(w7)));
    }
    if (e + 4 <= hi) {
        int s0 = src_sorted[e + 0], s1 = src_sorted[e + 1];
        int s2 = src_sorted[e + 2], s3 = src_sorted[e + 3];
        unsigned int w0 = zsb[(size_t)s0 * 32 + c];
        unsigned int w1 = zsb[(size_t)s1 * 32 + c];
        unsigned int w2 = zsb[(size_t)s2 * 32 + c];
        unsigned int w3 = zsb[(size_t)s3 * 32 + c];
        ax += (bf_lo(w0) + bf_lo(w1)) + (bf_lo(w2) + bf_lo(w3));
        ay += (bf_hi(w0) + bf_hi(w1)) + (bf_hi(w2) + bf_hi(w3));
        e += 4;
    }
    for (; e < hi; ++e) {
        int s = src_sorted[e];
        unsigned int ws = zsb[(size_t)s * 32 + c];
        ax += bf_lo(ws);
        ay += bf_hi(ws);
    }
    float di = dinv[i];
    float2 bb = *reinterpret_cast<const float2*>(&b2[2 * c]);
    float2 o = {di * ax + bb.x, di * ay + bb.y};
    *reinterpret_cast<float2*>(&out[(size_t)i * 64 + 2 * c]) = o;
}

// ---------------- launch ----------------

static inline size_t alignup(size_t v) { return (v + 255) & ~(size_t)255; }

extern "C" void kernel_launch(void* const* d_in, const int* in_sizes, int n_in,
                              void* d_out, int out_size, void* d_ws, size_t ws_size,
                              hipStream_t stream) {
    const float* x  = (const float*)d_in[0];
    const void*  ei = d_in[1];
    const float* W1 = (const float*)d_in[2];
    const float* b1 = (const float*)d_in[3];
    const float* W2 = (const float*)d_in[4];
    const float* b2 = (const float*)d_in[5];

    const int n = in_sizes[0] / 128;   // 100000
    const int e = in_sizes[1] / 2;     // 3200000

    // Region aliasing: the bucketed pairs array is dead before k_gemm128
    // writes hsb (stream-ordered), so they share one region.
    char* p = (char*)d_ws;
    auto take = [&](size_t bytes) { char* q = p; p += alignup(bytes); return q; };
    size_t pairs_bytes = (size_t)e * 8;            // 25.6 MB
    size_t hsb_bytes   = (size_t)n * 64 * 4;       // 25.6 MB
    size_t regA_bytes  = pairs_bytes > hsb_bytes ? pairs_bytes : hsb_bytes;
    char* regA = (char*)take(regA_bytes);
    unsigned long long* pairs = (unsigned long long*)regA;
    unsigned int*       hsb   = (unsigned int*)regA;

    float*        h2         = (float*)take((size_t)n * 128 * 4);
    int*          is64       = (int*)  take(4);
    float*        dinv       = (float*)take((size_t)n * 4);
    int*          row_ptr    = (int*)  take((size_t)(n + 1) * 4);
    int*          bkt_cnt    = (int*)  take(512 * 4);
    int*          bkt_base   = (int*)  take(513 * 4);
    int*          bkt_cursor = (int*)  take(512 * 4);
    int*          src_sorted = (int*)  take((size_t)e * 4);
    unsigned int* zsb        = (unsigned int*)take((size_t)n * 32 * 4);
    if ((size_t)(p - (char*)d_ws) > ws_size) return;  // ws too small -> fail loudly

    const int nb_bkt  = (n + 255) >> 8;             // 391 buckets of 256 nodes
    const int nb_chnk = (e + BKT_CH - 1) / BKT_CH;  // 196 chunks

    k_detect64<<<1, 256, 0, stream>>>((const unsigned int*)ei, e, is64);
    k_zero512<<<1, 512, 0, stream>>>(bkt_cnt);
    k_hist<<<nb_chnk, 256, 0, stream>>>(ei, e, is64, bkt_cnt);
    k_scan_bkt<<<1, 512, 0, stream>>>(bkt_cnt, bkt_base, bkt_cursor, nb_bkt);
    k_bucket<<<nb_chnk, 256, 0, stream>>>(ei, e, is64, bkt_cursor, pairs);
    k_place_deg<<<nb_bkt, 256, 0, stream>>>(pairs, bkt_base, n, nb_bkt,
                                            row_ptr, dinv, src_sorted);

    k_gemm128<<<(n + 63) / 64, 256, 0, stream>>>(x, W1, dinv, hsb, n);
    k_agg1<<<n, 64, 0, stream>>>(hsb, dinv, row_ptr, src_sorted, b1, h2);
    k_gemm64<<<(n + 63) / 64, 256, 0, stream>>>(h2, W2, dinv, zsb, n);
    k_agg2<<<(n + 1) / 2, 64, 0, stream>>>(zsb, dinv, row_ptr, src_sorted, b2, (float*)d_out, n);
}

// Round 8
// 353.903 us; speedup vs baseline: 1.5471x; 1.0283x over previous
//
#include <hip/hip_runtime.h>
#include <cstdint>
#include <cstddef>

// ---- bf16 pack/unpack helpers (RNE) ----
static __device__ __forceinline__ unsigned int f2bf_rne(float f) {
    unsigned int u = __float_as_uint(f);
    unsigned int r = 0x7FFFu + ((u >> 16) & 1u);
    return (u + r) >> 16;
}
static __device__ __forceinline__ unsigned int pack_bf2(float lo, float hi) {
    return f2bf_rne(lo) | (f2bf_rne(hi) << 16);
}
static __device__ __forceinline__ float bf_lo(unsigned int w) {
    return __uint_as_float(w << 16);
}
static __device__ __forceinline__ float bf_hi(unsigned int w) {
    return __uint_as_float(w & 0xFFFF0000u);
}

#define BKT_CH 8192    // edges per chunk-block (fits LDS staging: 2x32KB)

// ---------------- CSR build ----------------
// R6 lesson: every per-edge GLOBAL atomic costs ~30B of HBM write traffic.
// Zero per-edge global atomics; bucket reservations LDS-aggregated.
// R8: pairs packed to u32 ((d&255)<<24 | src, src<2^17), k_bucket single-read
// via LDS chunk staging.

__global__ void k_detect64(const unsigned int* ei, int e, int* is64) {
    __shared__ int nonzero;
    if (threadIdx.x == 0) nonzero = 0;
    __syncthreads();
    for (int i = threadIdx.x; i < 4096; i += blockDim.x) {
        size_t k = (size_t)((unsigned long long)i * (unsigned long long)e / 4096ull);
        if (ei[2 * k + 1] != 0u) nonzero = 1;   // racy OR, fine
    }
    __syncthreads();
    if (threadIdx.x == 0) *is64 = nonzero ? 0 : 1;
}

__global__ void k_zero512(int* p) { p[threadIdx.x] = 0; }

// Pass 0: bucket histogram (bucket = dst>>8). LDS-aggregated.
__global__ __launch_bounds__(256) void k_hist(const void* ei_raw, int e, const int* is64,
                                              int* __restrict__ bkt_cnt) {
    __shared__ int lcnt[512];
    int t = threadIdx.x;
    for (int j = t; j < 512; j += 256) lcnt[j] = 0;
    __syncthreads();
    int lo = blockIdx.x * BKT_CH;
    int hi = lo + BKT_CH; if (hi > e) hi = e;
    if (*is64) {
        const long long* p = (const long long*)ei_raw;
        for (int i = lo + t; i < hi; i += 256)
            atomicAdd(&lcnt[((int)p[(size_t)e + i]) >> 8], 1);
    } else {
        const int* p = (const int*)ei_raw;
        for (int i = lo + t; i < hi; i += 256)
            atomicAdd(&lcnt[p[(size_t)e + i] >> 8], 1);
    }
    __syncthreads();
    for (int j = t; j < 512; j += 256)
        if (lcnt[j]) atomicAdd(&bkt_cnt[j], lcnt[j]);
}

// Exclusive scan of bucket counts -> bkt_base[0..nb], bkt_cursor. One block.
__global__ __launch_bounds__(512) void k_scan_bkt(const int* __restrict__ bkt_cnt,
                                                  int* __restrict__ bkt_base,
                                                  int* __restrict__ bkt_cursor, int nb) {
    __shared__ int s[512];
    int t = threadIdx.x;
    int v = (t < nb) ? bkt_cnt[t] : 0;
    s[t] = v;
    __syncthreads();
    #pragma unroll
    for (int d = 1; d < 512; d <<= 1) {
        int tmp = (t >= d) ? s[t - d] : 0;
        __syncthreads();
        s[t] += tmp;
        __syncthreads();
    }
    if (t < nb) {
        int b = s[t] - v;
        bkt_base[t]   = b;
        bkt_cursor[t] = b;
    }
    if (t == 511) bkt_base[nb] = s[511];   // grand total (bins >= nb are 0)
}

// Pass 1: bucket the edges. One block per 8K-edge chunk; edges staged in LDS
// during the histogram pass (single global edge-list read), then scattered as
// packed u32 at LDS-reserved offsets.
__global__ __launch_bounds__(256) void k_bucket(const void* ei_raw, int e, const int* is64,
                                                int* __restrict__ bkt_cursor,
                                                unsigned int* __restrict__ pout) {
    __shared__ int ldst[BKT_CH];
    __shared__ int lsrc[BKT_CH];
    __shared__ int lcnt[512];
    __shared__ int lbase[512];
    int t = threadIdx.x;
    int lo = blockIdx.x * BKT_CH;
    int hi = lo + BKT_CH; if (hi > e) hi = e;
    int m = hi - lo;
    for (int j = t; j < 512; j += 256) lcnt[j] = 0;
    __syncthreads();
    bool w64 = (*is64 != 0);
    const long long* p64 = (const long long*)ei_raw;
    const int*       p32 = (const int*)ei_raw;
    for (int idx = t; idx < m; idx += 256) {
        size_t i = (size_t)lo + idx;
        int s, d;
        if (w64) { s = (int)p64[i]; d = (int)p64[(size_t)e + i]; }
        else     { s = p32[i];      d = p32[(size_t)e + i]; }
        ldst[idx] = d;
        lsrc[idx] = s;
        atomicAdd(&lcnt[d >> 8], 1);
    }
    __syncthreads();
    for (int j = t; j < 512; j += 256) {
        int c = lcnt[j];
        lbase[j] = c ? atomicAdd(&bkt_cursor[j], c) : 0;
        lcnt[j] = 0;                        // running offset for scatter
    }
    __syncthreads();
    for (int idx = t; idx < m; idx += 256) {
        int d = ldst[idx], s = lsrc[idx];
        int b = d >> 8;
        int pos = lbase[b] + atomicAdd(&lcnt[b], 1);
        pout[pos] = ((unsigned int)(d & 255) << 24) | (unsigned int)s;
    }
}

// Pass 2: one block per bucket (256 nodes). Per-node counts in LDS -> local
// scan gives row_ptr + dinv (deg = cnt + 1 self-loop); LDS cursors scatter
// src into src_sorted. Single-block window -> full-line writebacks.
__global__ __launch_bounds__(256) void k_place_deg(const unsigned int* __restrict__ pairs,
                                                   const int* __restrict__ bkt_base,
                                                   int n, int nb,
                                                   int* __restrict__ row_ptr,
                                                   float* __restrict__ dinv,
                                                   int* __restrict__ src_sorted) {
    __shared__ int lcnt[256];
    __shared__ int ls[256];
    __shared__ int lcur[256];
    int b = blockIdx.x;
    int t = threadIdx.x;
    int base = bkt_base[b], end = bkt_base[b + 1];
    lcnt[t] = 0;
    __syncthreads();
    for (int i = base + t; i < end; i += 256)
        atomicAdd(&lcnt[__builtin_nontemporal_load(&pairs[i]) >> 24], 1);
    __syncthreads();
    int v = lcnt[t];
    ls[t] = v;
    __syncthreads();
    #pragma unroll
    for (int d = 1; d < 256; d <<= 1) {
        int tmp = (t >= d) ? ls[t - d] : 0;
        __syncthreads();
        ls[t] += tmp;
        __syncthreads();
    }
    int nodebase = base + ls[t] - v;       // exclusive within bucket
    int node = (b << 8) + t;
    if (node < n) {
        row_ptr[node] = nodebase;
        dinv[node] = rsqrtf((float)(v + 1));
    }
    lcur[t] = nodebase;
    __syncthreads();
    for (int i = base + t; i < end; i += 256) {
        unsigned int pr = __builtin_nontemporal_load(&pairs[i]);
        int pos = atomicAdd(&lcur[pr >> 24], 1);
        src_sorted[pos] = (int)(pr & 0x00FFFFFFu);
    }
    if (t == 0 && b == nb - 1) row_ptr[n] = end;
}

// ---------------- GEMMs (f32 VALU, LDS-tiled) ----------------
// Epilogues scale by dinv[row] and pack to bf16 pairs (halves gather bytes
// downstream: R3 k_agg1 was L3-service-bound).

// hsb[m][c/2] = pack_bf16( dinv[m] * (A[m]@W)[c..c+1] ), K=128, N=128. A f32.
__global__ __launch_bounds__(256) void k_gemm128(const float* __restrict__ A,
                                                 const float* __restrict__ W,
                                                 const float* __restrict__ dinv,
                                                 unsigned int* __restrict__ hsb, int M) {
    __shared__ float sA[64][36];
    __shared__ float sW[32][128];
    int tid = threadIdx.x;
    int tx = tid & 15;   // cols tx*8 .. +7
    int ty = tid >> 4;   // rows ty*4 .. +3
    int row0 = blockIdx.x * 64;
    float acc[4][8] = {};
    for (int k0 = 0; k0 < 128; k0 += 32) {
        __syncthreads();
        for (int i = tid; i < 512; i += 256) {
            int r = i >> 3, c4 = i & 7;
            float4 v = {0.f, 0.f, 0.f, 0.f};
            int gr = row0 + r;
            if (gr < M) v = *reinterpret_cast<const float4*>(&A[(size_t)gr * 128 + k0 + c4 * 4]);
            *reinterpret_cast<float4*>(&sA[r][c4 * 4]) = v;
        }
        for (int i = tid; i < 1024; i += 256) {
            int r = i >> 5, c4 = i & 31;
            *reinterpret_cast<float4*>(&sW[r][c4 * 4]) =
                *reinterpret_cast<const float4*>(&W[(size_t)(k0 + r) * 128 + c4 * 4]);
        }
        __syncthreads();
        #pragma unroll
        for (int k = 0; k < 32; k += 4) {
            float4 a[4];
            #pragma unroll
            for (int r = 0; r < 4; ++r)
                a[r] = *reinterpret_cast<const float4*>(&sA[ty * 4 + r][k]);
            #pragma unroll
            for (int kk = 0; kk < 4; ++kk) {
                float4 w0 = *reinterpret_cast<const float4*>(&sW[k + kk][tx * 8]);
                float4 w1 = *reinterpret_cast<const float4*>(&sW[k + kk][tx * 8 + 4]);
                #pragma unroll
                for (int r = 0; r < 4; ++r) {
                    float av = (&a[r].x)[kk];
                    acc[r][0] += av * w0.x; acc[r][1] += av * w0.y;
                    acc[r][2] += av * w0.z; acc[r][3] += av * w0.w;
                    acc[r][4] += av * w1.x; acc[r][5] += av * w1.y;
                    acc[r][6] += av * w1.z; acc[r][7] += av * w1.w;
                }
            }
        }
    }
    #pragma unroll
    for (int r = 0; r < 4; ++r) {
        int gr = row0 + ty * 4 + r;
        if (gr < M) {
            float di = dinv[gr];
            uint4 o;
            o.x = pack_bf2(acc[r][0] * di, acc[r][1] * di);
            o.y = pack_bf2(acc[r][2] * di, acc[r][3] * di);
            o.z = pack_bf2(acc[r][4] * di, acc[r][5] * di);
            o.w = pack_bf2(acc[r][6] * di, acc[r][7] * di);
            *reinterpret_cast<uint4*>(&hsb[(size_t)gr * 64 + tx * 4]) = o;
        }
    }
}

// zsb[m][c/2] = pack_bf16( dinv[m] * (A[m]@W)[c..c+1] ), K=128, N=64.
// A is bf16x2 packed [M][64] (h2b from k_agg1), unpacked to f32 in LDS.
__global__ __launch_bounds__(256) void k_gemm64(const unsigned int* __restrict__ Ab,
                                                const float* __restrict__ W,
                                                const float* __restrict__ dinv,
                                                unsigned int* __restrict__ zsb, int M) {
    __shared__ float sA[64][36];
    __shared__ float sW[32][64];
    int tid = threadIdx.x;
    int tx = tid & 15;   // cols tx*4 .. +3
    int ty = tid >> 4;   // rows ty*4 .. +3
    int row0 = blockIdx.x * 64;
    float acc[4][4] = {};
    for (int k0 = 0; k0 < 128; k0 += 32) {
        __syncthreads();
        // stage A tile 64x32 f32 from bf16 pairs: words (k0/2)..(k0/2+15)
        for (int i = tid; i < 1024; i += 256) {
            int r = i >> 4, w = i & 15;
            int gr = row0 + r;
            unsigned int pv = (gr < M) ? Ab[(size_t)gr * 64 + (k0 >> 1) + w] : 0u;
            sA[r][2 * w]     = bf_lo(pv);
            sA[r][2 * w + 1] = bf_hi(pv);
        }
        for (int i = tid; i < 512; i += 256) {
            int r = i >> 4, c4 = i & 15;
            *reinterpret_cast<float4*>(&sW[r][c4 * 4]) =
                *reinterpret_cast<const float4*>(&W[(size_t)(k0 + r) * 64 + c4 * 4]);
        }
        __syncthreads();
        #pragma unroll
        for (int k = 0; k < 32; k += 4) {
            float4 a[4];
            #pragma unroll
            for (int r = 0; r < 4; ++r)
                a[r] = *reinterpret_cast<const float4*>(&sA[ty * 4 + r][k]);
            #pragma unroll
            for (int kk = 0; kk < 4; ++kk) {
                float4 w = *reinterpret_cast<const float4*>(&sW[k + kk][tx * 4]);
                #pragma unroll
                for (int r = 0; r < 4; ++r) {
                    float av = (&a[r].x)[kk];
                    acc[r][0] += av * w.x; acc[r][1] += av * w.y;
                    acc[r][2] += av * w.z; acc[r][3] += av * w.w;
                }
            }
        }
    }
    #pragma unroll
    for (int r = 0; r < 4; ++r) {
        int gr = row0 + ty * 4 + r;
        if (gr < M) {
            float di = dinv[gr];
            uint2 o;
            o.x = pack_bf2(acc[r][0] * di, acc[r][1] * di);
            o.y = pack_bf2(acc[r][2] * di, acc[r][3] * di);
            *reinterpret_cast<uint2*>(&zsb[(size_t)gr * 32 + tx * 2]) = o;
        }
    }
}

// ---------------- Aggregation ----------------
// bf16x2 payload: one dword per thread per row; f32 accumulate; x8 unroll
// keeps 8 row-loads in flight. nt loads on src_sorted (read-once stream) and
// nt store on h2b keep L2 capacity for the hsb gather.

// h2b[i][c] = pack_bf16(relu(dinv[i]*sum + b1[2c..2c+1])), one wave per node.
__global__ __launch_bounds__(64) void k_agg1(const unsigned int* __restrict__ hsb,
                                             const float* __restrict__ dinv,
                                             const int* __restrict__ row_ptr,
                                             const int* __restrict__ src_sorted,
                                             const float* __restrict__ b1,
                                             unsigned int* __restrict__ h2b) {
    int i = blockIdx.x;
    int c = threadIdx.x;          // channel pair 2c, 2c+1
    unsigned int w = hsb[(size_t)i * 64 + c];
    float ax = bf_lo(w), ay = bf_hi(w);
    int lo = row_ptr[i], hi = row_ptr[i + 1];
    int e = lo;
    for (; e + 8 <= hi; e += 8) {
        int s0 = __builtin_nontemporal_load(&src_sorted[e + 0]);
        int s1 = __builtin_nontemporal_load(&src_sorted[e + 1]);
        int s2 = __builtin_nontemporal_load(&src_sorted[e + 2]);
        int s3 = __builtin_nontemporal_load(&src_sorted[e + 3]);
        int s4 = __builtin_nontemporal_load(&src_sorted[e + 4]);
        int s5 = __builtin_nontemporal_load(&src_sorted[e + 5]);
        int s6 = __builtin_nontemporal_load(&src_sorted[e + 6]);
        int s7 = __builtin_nontemporal_load(&src_sorted[e + 7]);
        unsigned int w0 = hsb[(size_t)s0 * 64 + c];
        unsigned int w1 = hsb[(size_t)s1 * 64 + c];
        unsigned int w2 = hsb[(size_t)s2 * 64 + c];
        unsigned int w3 = hsb[(size_t)s3 * 64 + c];
        unsigned int w4 = hsb[(size_t)s4 * 64 + c];
        unsigned int w5 = hsb[(size_t)s5 * 64 + c];
        unsigned int w6 = hsb[(size_t)s6 * 64 + c];
        unsigned int w7 = hsb[(size_t)s7 * 64 + c];
        ax += ((bf_lo(w0) + bf_lo(w1)) + (bf_lo(w2) + bf_lo(w3)))
            + ((bf_lo(w4) + bf_lo(w5)) + (bf_lo(w6) + bf_lo(w7)));
        ay += ((bf_hi(w0) + bf_hi(w1)) + (bf_hi(w2) + bf_hi(w3)))
            + ((bf_hi(w4) + bf_hi(w5)) + (bf_hi(w6) + bf_hi(w7)));
    }
    if (e + 4 <= hi) {
        int s0 = __builtin_nontemporal_load(&src_sorted[e + 0]);
        int s1 = __builtin_nontemporal_load(&src_sorted[e + 1]);
        int s2 = __builtin_nontemporal_load(&src_sorted[e + 2]);
        int s3 = __builtin_nontemporal_load(&src_sorted[e + 3]);
        unsigned int w0 = hsb[(size_t)s0 * 64 + c];
        unsigned int w1 = hsb[(size_t)s1 * 64 + c];
        unsigned int w2 = hsb[(size_t)s2 * 64 + c];
        unsigned int w3 = hsb[(size_t)s3 * 64 + c];
        ax += (bf_lo(w0) + bf_lo(w1)) + (bf_lo(w2) + bf_lo(w3));
        ay += (bf_hi(w0) + bf_hi(w1)) + (bf_hi(w2) + bf_hi(w3));
        e += 4;
    }
    for (; e < hi; ++e) {
        int s = __builtin_nontemporal_load(&src_sorted[e]);
        unsigned int ws = hsb[(size_t)s * 64 + c];
        ax += bf_lo(ws);
        ay += bf_hi(ws);
    }
    float di = dinv[i];
    float2 bb = *reinterpret_cast<const float2*>(&b1[2 * c]);
    float v0 = di * ax + bb.x;
    float v1 = di * ay + bb.y;
    unsigned int pv = pack_bf2(v0 > 0.f ? v0 : 0.f, v1 > 0.f ? v1 : 0.f);
    __builtin_nontemporal_store(pv, &h2b[(size_t)i * 64 + c]);
}

// out[i][2c..2c+1] = dinv[i]*(zsb_sum) + b2; 2 nodes per 64-thread block.
__global__ __launch_bounds__(64) void k_agg2(const unsigned int* __restrict__ zsb,
                                             const float* __restrict__ dinv,
                                             const int* __restrict__ row_ptr,
                                             const int* __restrict__ src_sorted,
                                             const float* __restrict__ b2,
                                             float* __restrict__ out, int n) {
    int i = blockIdx.x * 2 + (threadIdx.x >> 5);
    int c = threadIdx.x & 31;     // channel pair 2c, 2c+1
    if (i >= n) return;
    unsigned int w = zsb[(size_t)i * 32 + c];
    float ax = bf_lo(w), ay = bf_hi(w);
    int lo = row_ptr[i], hi = row_ptr[i + 1];
    int e = lo;
    for (; e + 8 <= hi; e += 8) {
        int s0 = __builtin_nontemporal_load(&src_sorted[e + 0]);
        int s1 = __builtin_nontemporal_load(&src_sorted[e + 1]);
        int s2 = __builtin_nontemporal_load(&src_sorted[e + 2]);
        int s3 = __builtin_nontemporal_load(&src_sorted[e + 3]);
        int s4 = __builtin_nontemporal_load(&src_sorted[e + 4]);
        int s5 = __builtin_nontemporal_load(&src_sorted[e + 5]);
        int s6 = __builtin_nontemporal_load(&src_sorted[e + 6]);
        int s7 = __builtin_nontemporal_load(&src_sorted[e + 7]);
        unsigned int w0 = zsb[(size_t)s0 * 32 + c];
        unsigned int w1 = zsb[(size_t)s1 * 32 + c];
        unsigned int w2 = zsb[(size_t)s2 * 32 + c];
        unsigned int w3 = zsb[(size_t)s3 * 32 + c];
        unsigned int w4 = zsb[(size_t)s4 * 32 + c];
        unsigned int w5 = zsb[(size_t)s5 * 32 + c];
        unsigned int w6 = zsb[(size_t)s6 * 32 + c];
        unsigned int w7 = zsb[(size_t)s7 * 32 + c];
        ax += ((bf_lo(w0) + bf_lo(w1)) + (bf_lo(w2) + bf_lo(w3)))
            + ((bf_lo(w4) + bf_lo(w5)) + (bf_lo(w6) + bf_lo(w7)));
        ay += ((bf_hi(w0) + bf_hi(w1)) + (bf_hi(w2) + bf_hi(w3)))
            + ((bf_hi(w4) + bf_hi(w5)) + (bf_hi(w6) + bf_hi(w7)));
    }
    if (e + 4 <= hi) {
        int s0 = __builtin_nontemporal_load(&src_sorted[e + 0]);
        int s1 = __builtin_nontemporal_load(&src_sorted[e + 1]);
        int s2 = __builtin_nontemporal_load(&src_sorted[e + 2]);
        int s3 = __builtin_nontemporal_load(&src_sorted[e + 3]);
        unsigned int w0 = zsb[(size_t)s0 * 32 + c];
        unsigned int w1 = zsb[(size_t)s1 * 32 + c];
        unsigned int w2 = zsb[(size_t)s2 * 32 + c];
        unsigned int w3 = zsb[(size_t)s3 * 32 + c];
        ax += (bf_lo(w0) + bf_lo(w1)) + (bf_lo(w2) + bf_lo(w3));
        ay += (bf_hi(w0) + bf_hi(w1)) + (bf_hi(w2) + bf_hi(w3));
        e += 4;
    }
    for (; e < hi; ++e) {
        int s = __builtin_nontemporal_load(&src_sorted[e]);
        unsigned int ws = zsb[(size_t)s * 32 + c];
        ax += bf_lo(ws);
        ay += bf_hi(ws);
    }
    float di = dinv[i];
    float2 bb = *reinterpret_cast<const float2*>(&b2[2 * c]);
    float2 o = {di * ax + bb.x, di * ay + bb.y};
    *reinterpret_cast<float2*>(&out[(size_t)i * 64 + 2 * c]) = o;
}

// ---------------- launch ----------------

static inline size_t alignup(size_t v) { return (v + 255) & ~(size_t)255; }

extern "C" void kernel_launch(void* const* d_in, const int* in_sizes, int n_in,
                              void* d_out, int out_size, void* d_ws, size_t ws_size,
                              hipStream_t stream) {
    const float* x  = (const float*)d_in[0];
    const void*  ei = d_in[1];
    const float* W1 = (const float*)d_in[2];
    const float* b1 = (const float*)d_in[3];
    const float* W2 = (const float*)d_in[4];
    const float* b2 = (const float*)d_in[5];

    const int n = in_sizes[0] / 128;   // 100000
    const int e = in_sizes[1] / 2;     // 3200000

    // Region aliasing: packed pairs (u32, 12.8 MB) are dead before k_gemm128
    // writes hsb (stream-ordered), so they share one region.
    char* p = (char*)d_ws;
    auto take = [&](size_t bytes) { char* q = p; p += alignup(bytes); return q; };
    size_t pairs_bytes = (size_t)e * 4;            // 12.8 MB
    size_t hsb_bytes   = (size_t)n * 64 * 4;       // 25.6 MB
    size_t regA_bytes  = pairs_bytes > hsb_bytes ? pairs_bytes : hsb_bytes;
    char* regA = (char*)take(regA_bytes);
    unsigned int* pairs = (unsigned int*)regA;
    unsigned int* hsb   = (unsigned int*)regA;

    unsigned int* h2b        = (unsigned int*)take((size_t)n * 64 * 4);   // bf16x2
    int*          is64       = (int*)  take(4);
    float*        dinv       = (float*)take((size_t)n * 4);
    int*          row_ptr    = (int*)  take((size_t)(n + 1) * 4);
    int*          bkt_cnt    = (int*)  take(512 * 4);
    int*          bkt_base   = (int*)  take(513 * 4);
    int*          bkt_cursor = (int*)  take(512 * 4);
    int*          src_sorted = (int*)  take((size_t)e * 4);
    unsigned int* zsb        = (unsigned int*)take((size_t)n * 32 * 4);
    if ((size_t)(p - (char*)d_ws) > ws_size) return;  // ws too small -> fail loudly

    const int nb_bkt  = (n + 255) >> 8;             // 391 buckets of 256 nodes
    const int nb_chnk = (e + BKT_CH - 1) / BKT_CH;  // 391 chunks

    k_detect64<<<1, 256, 0, stream>>>((const unsigned int*)ei, e, is64);
    k_zero512<<<1, 512, 0, stream>>>(bkt_cnt);
    k_hist<<<nb_chnk, 256, 0, stream>>>(ei, e, is64, bkt_cnt);
    k_scan_bkt<<<1, 512, 0, stream>>>(bkt_cnt, bkt_base, bkt_cursor, nb_bkt);
    k_bucket<<<nb_chnk, 256, 0, stream>>>(ei, e, is64, bkt_cursor, pairs);
    k_place_deg<<<nb_bkt, 256, 0, stream>>>(pairs, bkt_base, n, nb_bkt,
                                            row_ptr, dinv, src_sorted);

    k_gemm128<<<(n + 63) / 64, 256, 0, stream>>>(x, W1, dinv, hsb, n);
    k_agg1<<<n, 64, 0, stream>>>(hsb, dinv, row_ptr, src_sorted, b1, h2b);
    k_gemm64<<<(n + 63) / 64, 256, 0, stream>>>(h2b, W2, dinv, zsb, n);
    k_agg2<<<(n + 1) / 2, 64, 0, stream>>>(zsb, dinv, row_ptr, src_sorted, b2, (float*)d_out, n);
}